// Round 2
// baseline (1119.238 us; speedup 1.0000x reference)
//
#include <hip/hip_runtime.h>

#define LVL 8
#define C 8192
#define D 128
#define P 8
#define F 4
#define K 4
#define S 4
#define NF 16384
#define NTOT (LVL*C)   // 65536

typedef __bf16 bf16;
typedef bf16 bf16x4 __attribute__((ext_vector_type(4)));
typedef bf16 bf16x8 __attribute__((ext_vector_type(8)));
typedef float f32x4 __attribute__((ext_vector_type(4)));

__device__ __forceinline__ f32x4 mfma16(bf16x8 a, bf16x8 b, f32x4 c) {
  return __builtin_amdgcn_mfma_f32_16x16x32_bf16(a, b, c, 0, 0, 0);
}
__device__ __forceinline__ bf16x4 b4(f32x4 v) {
  bf16x4 r; r[0]=(bf16)v[0]; r[1]=(bf16)v[1]; r[2]=(bf16)v[2]; r[3]=(bf16)v[3]; return r;
}
__device__ __forceinline__ float sigm(float x) { return __builtin_amdgcn_rcpf(1.f + __expf(-x)); }
__device__ __forceinline__ float tanh_(float x) { return 1.f - 2.f*__builtin_amdgcn_rcpf(1.f + __expf(2.f*x)); }

// ---- dtype-flexible accessors (f=1: float32 storage, f=0: bf16 storage) ----
__device__ __forceinline__ float ldf(const void* b, long i, int f) {
  return f ? ((const float*)b)[i] : (float)((const bf16*)b)[i];
}
__device__ __forceinline__ bf16x8 ldx8(const void* b, long i, int f) {
  if (f) {
    f32x4 a = *(const f32x4*)((const float*)b + i);
    f32x4 c = *(const f32x4*)((const float*)b + i + 4);
    bf16x8 r;
    r[0]=(bf16)a[0]; r[1]=(bf16)a[1]; r[2]=(bf16)a[2]; r[3]=(bf16)a[3];
    r[4]=(bf16)c[0]; r[5]=(bf16)c[1]; r[6]=(bf16)c[2]; r[7]=(bf16)c[3];
    return r;
  }
  return *(const bf16x8*)((const bf16*)b + i);
}
__device__ __forceinline__ f32x4 ld4f(const void* b, long i, int f) {
  if (f) return *(const f32x4*)((const float*)b + i);
  bf16x4 t = *(const bf16x4*)((const bf16*)b + i);
  f32x4 r; r[0]=(float)t[0]; r[1]=(float)t[1]; r[2]=(float)t[2]; r[3]=(float)t[3]; return r;
}
__device__ __forceinline__ void st4(void* b, long i, int f, f32x4 v) {
  if (f) *(f32x4*)((float*)b + i) = v;
  else   *(bf16x4*)((bf16*)b + i) = b4(v);
}

// ---------------------------------------------------------------------------
// One GRU scan step: D[gate][seq] = U x hT + W x xT (+bias via acc init),
// elementwise, write new h (transposed) to hout. NT = number of 16-seq tiles.
// ---------------------------------------------------------------------------
template<int NT>
__device__ __forceinline__ void gru_step(
    const bf16x8 (&AU)[3][4], const bf16x8 (&AW)[3][4],
    const f32x4& zb, const f32x4& rb, const f32x4& nbx, const f32x4& nbh,
    const bf16 (* __restrict__ hbuf)[136], const bf16 (* __restrict__ xbuf)[136],
    int l15, int quad, int gc,
    f32x4 (&h)[NT], bf16 (*hout)[136])
{
  f32x4 aZ[NT], aR[NT], aNx[NT], aNh[NT];
#pragma unroll
  for (int nt = 0; nt < NT; nt++) { aZ[nt]=zb; aR[nt]=rb; aNx[nt]=nbx; aNh[nt]=nbh; }
#pragma unroll
  for (int kt = 0; kt < 4; kt++) {
    bf16x8 Bh[NT], Bx[NT];
#pragma unroll
    for (int nt = 0; nt < NT; nt++) {
      Bh[nt] = *(const bf16x8*)&hbuf[nt*16 + l15][kt*32 + quad*8];
      Bx[nt] = *(const bf16x8*)&xbuf[nt*16 + l15][kt*32 + quad*8];
    }
#pragma unroll
    for (int nt = 0; nt < NT; nt++) {
      aZ[nt]  = mfma16(AU[0][kt], Bh[nt], aZ[nt]);
      aZ[nt]  = mfma16(AW[0][kt], Bx[nt], aZ[nt]);
      aR[nt]  = mfma16(AU[1][kt], Bh[nt], aR[nt]);
      aR[nt]  = mfma16(AW[1][kt], Bx[nt], aR[nt]);
      aNh[nt] = mfma16(AU[2][kt], Bh[nt], aNh[nt]);
      aNx[nt] = mfma16(AW[2][kt], Bx[nt], aNx[nt]);
    }
  }
#pragma unroll
  for (int nt = 0; nt < NT; nt++) {
    f32x4 hn = h[nt];
#pragma unroll
    for (int i = 0; i < 4; i++) {
      float z = sigm(aZ[nt][i]);
      float r = sigm(aR[nt][i]);
      float n = tanh_(aNx[nt][i] + r*aNh[nt][i]);
      hn[i] = z*hn[i] + (1.f - z)*n;
    }
    h[nt] = hn;
    *(bf16x4*)&hout[nt*16 + l15][gc] = b4(hn);
  }
}

// ---------------------------------------------------------------------------
// Fused per-level kernel (mode 0): 256 blocks x 512 thr, 32 classes/block.
//   Phase A: fn GRU (2 passes x 64 seqs, NT=4) + fe epilogue -> memfn + feT(LDS)
//   Phase B: member GRU (32 seqs, T=13; steps 9-12 read feT directly)
//   Phase C: super GRU (32 seqs, T=5; step 4 = m from registers) -> table + shadow
// mode 1 (glob): phase A only, 1 pass x 64 seqs, direct seq indexing.
// All gathers read the bf16 shadow table (16 B/lane instead of 32 B).
// NOTE: __launch_bounds__(512,1): LDS (102 KB) limits us to 1 block/CU anyway;
// a block is 8 waves on 4 SIMDs so the effective VGPR cap is 256/wave. The
// (512,2) variant capped VGPRs at 128 -> massive scratch spill (119 MB
// WRITE_SIZE/dispatch, rocprof round 1).
// ---------------------------------------------------------------------------
__global__ __launch_bounds__(512, 1) void level_kernel(
    const bf16* __restrict__ pUt, const bf16* __restrict__ pWt, const float* __restrict__ b2p,
    const bf16* __restrict__ wtT,
    const bf16* __restrict__ mUt, const bf16* __restrict__ mWt, const float* __restrict__ b2m,
    const bf16* __restrict__ sUt, const bf16* __restrict__ sWt, const float* __restrict__ b2s,
    const void* __restrict__ empty_params, const void* __restrict__ empty_members,
    const void* __restrict__ tabR, int tabRf,        // gather source (shadow bf16, or f32 table fallback)
    const int* __restrict__ fpi, const int* __restrict__ fri,
    const int* __restrict__ ppi, const int* __restrict__ spi,
    void* __restrict__ out, long memfnEB, long tabEB,
    bf16* __restrict__ shadowW,                      // shadow write base for this level's rows (may be null)
    const int* __restrict__ flagp, int mode)
{
  __shared__ __align__(16) bf16 hT[2][64][136];
  __shared__ __align__(16) bf16 xT[2][64][136];
  __shared__ __align__(16) bf16 feT[4][32][136];

  const int isf32 = *flagp;
  const int rf = (tabRf < 0) ? isf32 : tabRf;
  const int tid = threadIdx.x;
  const int w = tid >> 6;
  const int l15 = tid & 15;
  const int quad = (tid & 63) >> 4;
  const int gc = w*16 + quad*4;
  const int prow = tid >> 4;          // 0..31
  const int pc8 = (tid & 15) * 8;
  const int c0 = blockIdx.x * 32;

  bf16x8 AU[3][4], AW[3][4];
  f32x4 zb, rb, nbx, nbh;
  auto loadWB = [&](const bf16* Ut, const bf16* Wt, const float* b2) {
#pragma unroll
    for (int tr = 0; tr < 3; tr++)
#pragma unroll
      for (int kt = 0; kt < 4; kt++) {
        size_t o = (size_t)(tr*128 + w*16 + l15)*128 + kt*32 + quad*8;
        AU[tr][kt] = *(const bf16x8*)&Ut[o];
        AW[tr][kt] = *(const bf16x8*)&Wt[o];
      }
    zb  = *(const f32x4*)&b2[0*128 + gc];
    rb  = *(const f32x4*)&b2[1*128 + gc];
    nbx = *(const f32x4*)&b2[2*128 + gc];
    nbh = *(const f32x4*)&b2[3*128 + gc];
  };

  f32x4 hm[2];   // member result, carried into super phase

  // ================= Phase A: fn GRU + fe =================
  loadWB(pUt, pWt, b2p);
  const int npass = mode ? 1 : 2;
  for (int p = 0; p < npass; p++) {
    long sA[2]; int rA[2][4];
#pragma unroll
    for (int r = 0; r < 2; r++) {
      long s = mode ? ((long)blockIdx.x*64 + prow + 32*r)
                    : ((long)(c0 + prow)*4 + 2*p + r);
      sA[r] = s;
      int4 pi = *(const int4*)&fpi[s*4];
      rA[r][0]=pi.x; rA[r][1]=pi.y; rA[r][2]=pi.z; rA[r][3]=pi.w;
    }
    for (int i = tid; i < 64*136/2; i += 512) ((int*)hT)[i] = 0;
    { bf16x8 e = ldx8(empty_params, pc8, isf32);
      *(bf16x8*)&xT[0][prow][pc8]      = e;
      *(bf16x8*)&xT[0][prow + 32][pc8] = e; }
    __syncthreads();

    f32x4 h[4];
#pragma unroll
    for (int nt = 0; nt < 4; nt++) { h[nt][0]=0.f; h[nt][1]=0.f; h[nt][2]=0.f; h[nt][3]=0.f; }
    int buf = 0;
    for (int t = 0; t < 5; t++) {
      bf16x8 xn[2];
      if (t < 4) {
#pragma unroll
        for (int r = 0; r < 2; r++) xn[r] = ldx8(tabR, (long)rA[r][t]*128 + pc8, rf);
      }
      gru_step<4>(AU, AW, zb, rb, nbx, nbh,
                  (const bf16(*)[136])hT[buf], (const bf16(*)[136])xT[t&1],
                  l15, quad, gc, h, hT[1-buf]);
      if (t < 4) {
#pragma unroll
        for (int r = 0; r < 2; r++) *(bf16x8*)&xT[(t+1)&1][prow + 32*r][pc8] = xn[r];
      }
      __syncthreads();
      buf ^= 1;
    }
    // stage ret rows (transposed) into xT[0]
#pragma unroll
    for (int r = 0; r < 2; r++) {
      int ridx = fri[sA[r]];
      bf16x8 rv = ldx8(tabR, (long)ridx*128 + pc8, rf);
      *(bf16x8*)&xT[0][prow + 32*r][pc8] = rv;
    }
    __syncthreads();

    // fe GEMM: out = [h | ret] @ W_fn  (K=256)
    f32x4 acc[4];
#pragma unroll
    for (int nt = 0; nt < 4; nt++) { acc[nt][0]=0.f; acc[nt][1]=0.f; acc[nt][2]=0.f; acc[nt][3]=0.f; }
#pragma unroll
    for (int kt = 0; kt < 8; kt++) {
      bf16x8 A = *(const bf16x8*)&wtT[(size_t)(w*16 + l15)*256 + kt*32 + quad*8];
#pragma unroll
      for (int nt = 0; nt < 4; nt++) {
        bf16x8 B = (kt < 4) ? *(const bf16x8*)&hT[buf][nt*16 + l15][kt*32 + quad*8]
                            : *(const bf16x8*)&xT[0][nt*16 + l15][(kt-4)*32 + quad*8];
        acc[nt] = mfma16(A, B, acc[nt]);
      }
    }
#pragma unroll
    for (int nt = 0; nt < 4; nt++) {
      long s = mode ? ((long)blockIdx.x*64 + nt*16 + l15)
                    : ((long)(c0 + (nt&1)*16 + l15)*4 + 2*p + (nt>>1));
      st4(out, memfnEB + s*128 + gc, isf32, acc[nt]);
      if (!mode) *(bf16x4*)&feT[2*p + (nt>>1)][(nt&1)*16 + l15][gc] = b4(acc[nt]);
    }
    __syncthreads();
  }
  if (mode) return;

  // ================= Phase B: member GRU (T=13) =================
  loadWB(mUt, mWt, b2m);
  int rM[8];
  { int4 a = *(const int4*)&ppi[(size_t)(c0 + prow)*8];
    int4 b = *(const int4*)&ppi[(size_t)(c0 + prow)*8 + 4];
    rM[0]=a.x; rM[1]=a.y; rM[2]=a.z; rM[3]=a.w;
    rM[4]=b.x; rM[5]=b.y; rM[6]=b.z; rM[7]=b.w; }
  for (int i = tid; i < 32*136/2; i += 512) ((int*)hT)[i] = 0;
  { bf16x8 e = ldx8(empty_members, pc8, isf32);
    *(bf16x8*)&xT[0][prow][pc8] = e; }
  __syncthreads();

#pragma unroll
  for (int nt = 0; nt < 2; nt++) { hm[nt][0]=0.f; hm[nt][1]=0.f; hm[nt][2]=0.f; hm[nt][3]=0.f; }
  {
    int buf = 0;
    for (int t = 0; t < 13; t++) {
      bf16x8 xn;
      if (t < 8) xn = ldx8(tabR, (long)rM[t]*128 + pc8, rf);   // x for step t+1
      const bf16 (*xb)[136] = (t < 9) ? (const bf16(*)[136])xT[t&1]
                                      : (const bf16(*)[136])feT[t-9];
      gru_step<2>(AU, AW, zb, rb, nbx, nbh,
                  (const bf16(*)[136])hT[buf], xb, l15, quad, gc, hm, hT[1-buf]);
      if (t < 8) *(bf16x8*)&xT[(t+1)&1][prow][pc8] = xn;
      __syncthreads();
      buf ^= 1;
    }
  }

  // ================= Phase C: super GRU (T=5) =================
  loadWB(sUt, sWt, b2s);
  int rS[4];
  { int4 a = *(const int4*)&spi[(size_t)(c0 + prow)*4];
    rS[0]=a.x; rS[1]=a.y; rS[2]=a.z; rS[3]=a.w; }
  for (int i = tid; i < 32*136/2; i += 512) ((int*)hT)[i] = 0;
  { bf16x8 x0 = ldx8(tabR, (long)rS[0]*128 + pc8, rf);
    *(bf16x8*)&xT[0][prow][pc8] = x0; }
  __syncthreads();

  f32x4 hs[2];
#pragma unroll
  for (int nt = 0; nt < 2; nt++) { hs[nt][0]=0.f; hs[nt][1]=0.f; hs[nt][2]=0.f; hs[nt][3]=0.f; }
  {
    int buf = 0;
    for (int t = 0; t < 5; t++) {
      bf16x8 xn;
      if (t < 3) xn = ldx8(tabR, (long)rS[t+1]*128 + pc8, rf);
      gru_step<2>(AU, AW, zb, rb, nbx, nbh,
                  (const bf16(*)[136])hT[buf], (const bf16(*)[136])xT[t&1],
                  l15, quad, gc, hs, hT[1-buf]);
      if (t < 3) *(bf16x8*)&xT[(t+1)&1][prow][pc8] = xn;
      else if (t == 3) {   // stage m (registers) as x for step 4
#pragma unroll
        for (int nt = 0; nt < 2; nt++) *(bf16x4*)&xT[0][nt*16 + l15][gc] = b4(hm[nt]);
      }
      __syncthreads();
      buf ^= 1;
    }
  }
#pragma unroll
  for (int nt = 0; nt < 2; nt++) {
    long row = (long)(c0 + nt*16 + l15);
    st4(out, tabEB + row*128 + gc, isf32, hs[nt]);
    if (shadowW) *(bf16x4*)&shadowW[row*128 + gc] = b4(hs[nt]);
  }
}

// ---------------------------------------------------------------------------
// dtype detect: bf16-interpret first 128 u16 of basic_emb; any exponent>=128
// (|v|>=2) is impossible for genuine bf16 data here -> storage is float32.
// ---------------------------------------------------------------------------
__global__ void detect_kernel(const void* be, int* flag) {
  if (threadIdx.x == 0 && blockIdx.x == 0) {
    const unsigned short* u = (const unsigned short*)be;
    int f = 0;
    for (int i = 0; i < 128; i++) {
      unsigned e = (u[i] >> 7) & 0xFF;
      if (e >= 128) f = 1;
    }
    *flag = f;
  }
}

__global__ void convert_kernel(const void* pW, const void* pU, const void* mW, const void* mU,
                               const void* sW, const void* sU, const void* W_fn,
                               const void* pb, const void* mb, const void* sb,
                               bf16* pWt, bf16* pUt, bf16* mWt, bf16* mUt,
                               bf16* sWt, bf16* sUt, bf16* wtT,
                               float* b2p, float* b2m, float* b2s,
                               const int* flagp) {
  const int f = *flagp;
  int i = blockIdx.x*256 + threadIdx.x;
  const int TT = 384*128;
  if (i < 6*TT) {
    int which = i / TT, j = i - which*TT;
    int c = j >> 7, k = j & 127;
    const void* src = (which==0)?pW:(which==1)?pU:(which==2)?mW:(which==3)?mU:(which==4)?sW:sU;
    bf16* dst = (which==0)?pWt:(which==1)?pUt:(which==2)?mWt:(which==3)?mUt:(which==4)?sWt:sUt;
    dst[c*128 + k] = (bf16)ldf(src, (long)k*384 + c, f);
    return;
  }
  i -= 6*TT;
  if (i < 128*256) { int c = i >> 8, k = i & 255; wtT[c*256 + k] = (bf16)ldf(W_fn, (long)k*128 + c, f); return; }
  i -= 128*256;
  if (i < 3*512) {
    int which = i >> 9, j = i & 511;
    const void* b = (which==0)?pb:(which==1)?mb:sb;
    float* dst = (which==0)?b2p:(which==1)?b2m:b2s;
    int g = j >> 7, cc = j & 127;
    float v;
    if (g == 0)      v = ldf(b, cc, f)       + ldf(b, 384 + cc, f);
    else if (g == 1) v = ldf(b, 128 + cc, f) + ldf(b, 512 + cc, f);
    else if (g == 2) v = ldf(b, 256 + cc, f);
    else             v = ldf(b, 640 + cc, f);
    dst[j] = v;
  }
}

__global__ void level0_kernel(const int* __restrict__ basic_ids, const void* basic_emb,
                              void* out, bf16* __restrict__ shadow,
                              const int* __restrict__ flagp) {
  const int f = *flagp;
  int i = blockIdx.x*256 + threadIdx.x;   // < C*32
  int row = i >> 5, c4 = (i & 31) * 4;
  f32x4 v = ld4f(basic_emb, (long)basic_ids[row]*128 + c4, f);
  st4(out, (long)row*128 + c4, f, v);
  if (shadow) *(bf16x4*)&shadow[(long)row*128 + c4] = b4(v);
}

// ---------------------------------------------------------------------------
extern "C" void kernel_launch(void* const* d_in, const int* in_sizes, int n_in,
                              void* d_out, int out_size, void* d_ws, size_t ws_size,
                              hipStream_t stream) {
  const int* basic_ids      = (const int*)d_in[0];
  const int* prop_idx       = (const int*)d_in[1];
  const int* func_param_idx = (const int*)d_in[2];
  const int* func_ret_idx   = (const int*)d_in[3];
  const int* super_idx      = (const int*)d_in[4];
  const int* glob_param_idx = (const int*)d_in[5];
  const int* glob_ret_idx   = (const int*)d_in[6];
  const void* basic_emb     = d_in[7];
  const void* empty_params  = d_in[8];
  const void* empty_members = d_in[9];
  const void* W_fn = d_in[10];
  const void* pW = d_in[11]; const void* pU = d_in[12]; const void* pb = d_in[13];
  const void* mW = d_in[14]; const void* mU = d_in[15]; const void* mb = d_in[16];
  const void* sW = d_in[17]; const void* sU = d_in[18]; const void* sb = d_in[19];

  // d_out element layout: table [NTOT*128] | glob [NF*128] | memfn [7*C*F*128]
  const long GB = (long)NTOT*128;
  const long MB0 = GB + (long)NF*128;
  auto FEB = [&](int l) { return MB0 + (long)(l-1)*C*F*128; };

  char* wp = (char*)d_ws;
  auto carve = [&](size_t bytes) { char* p = wp; wp += (bytes + 255) & ~(size_t)255; return p; };
  int*  flag = (int*)carve(256);
  bf16* pWt = (bf16*)carve(384*128*2);
  bf16* pUt = (bf16*)carve(384*128*2);
  bf16* mWt = (bf16*)carve(384*128*2);
  bf16* mUt = (bf16*)carve(384*128*2);
  bf16* sWt = (bf16*)carve(384*128*2);
  bf16* sUt = (bf16*)carve(384*128*2);
  bf16* wtT = (bf16*)carve(128*256*2);
  float* b2p = (float*)carve(512*4);
  float* b2m = (float*)carve(512*4);
  float* b2s = (float*)carve(512*4);
  bf16* shadow = (bf16*)carve((size_t)NTOT*128*2);   // bf16 mirror of table, ~16.8 MB

  const bool useShadow = ((size_t)(wp - (char*)d_ws) <= ws_size);
  const void* tabR = useShadow ? (const void*)shadow : (const void*)d_out;
  const int tabRf  = useShadow ? 0 : -1;             // -1: use detected dtype flag
  bf16* shadowL0   = useShadow ? shadow : (bf16*)nullptr;

  detect_kernel<<<1, 64, 0, stream>>>(basic_emb, flag);
  {
    int total = 6*384*128 + 128*256 + 3*512;
    convert_kernel<<<(total + 255)/256, 256, 0, stream>>>(pW, pU, mW, mU, sW, sU, W_fn,
                                                          pb, mb, sb,
                                                          pWt, pUt, mWt, mUt, sWt, sUt, wtT,
                                                          b2p, b2m, b2s, flag);
  }
  level0_kernel<<<(C*32)/256, 256, 0, stream>>>(basic_ids, basic_emb, d_out, shadowL0, flag);

  for (int l = 1; l < LVL; l++) {
    level_kernel<<<C/32, 512, 0, stream>>>(
        pUt, pWt, b2p, wtT, mUt, mWt, b2m, sUt, sWt, b2s,
        empty_params, empty_members,
        tabR, tabRf,
        func_param_idx + (size_t)(l-1)*C*F*K,
        func_ret_idx   + (size_t)(l-1)*C*F,
        prop_idx       + (size_t)(l-1)*C*P,
        super_idx      + (size_t)(l-1)*C*S,
        d_out, FEB(l), (long)l*C*128,
        useShadow ? shadow + (size_t)l*C*128 : (bf16*)nullptr,
        flag, 0);
  }

  // global functions (NF seqs, T=5, 1 pass of 64 seqs/block) -> glob
  level_kernel<<<NF/64, 512, 0, stream>>>(
      pUt, pWt, b2p, wtT, mUt, mWt, b2m, sUt, sWt, b2s,
      empty_params, empty_members,
      tabR, tabRf,
      glob_param_idx, glob_ret_idx, nullptr, nullptr,
      d_out, GB, 0, (bf16*)nullptr,
      flag, 1);
}

// Round 3
// 1081.608 us; speedup vs baseline: 1.0348x; 1.0348x over previous
//
#include <hip/hip_runtime.h>

#define LVL 8
#define C 8192
#define D 128
#define P 8
#define F 4
#define K 4
#define S 4
#define NF 16384
#define NTOT (LVL*C)   // 65536

typedef __bf16 bf16;
typedef bf16 bf16x4 __attribute__((ext_vector_type(4)));
typedef bf16 bf16x8 __attribute__((ext_vector_type(8)));
typedef float f32x4 __attribute__((ext_vector_type(4)));

__device__ __forceinline__ f32x4 mfma16(bf16x8 a, bf16x8 b, f32x4 c) {
  return __builtin_amdgcn_mfma_f32_16x16x32_bf16(a, b, c, 0, 0, 0);
}
__device__ __forceinline__ bf16x4 b4(f32x4 v) {
  bf16x4 r; r[0]=(bf16)v[0]; r[1]=(bf16)v[1]; r[2]=(bf16)v[2]; r[3]=(bf16)v[3]; return r;
}
__device__ __forceinline__ float sigm(float x) { return __builtin_amdgcn_rcpf(1.f + __expf(-x)); }
__device__ __forceinline__ float tanh_(float x) { return 1.f - 2.f*__builtin_amdgcn_rcpf(1.f + __expf(2.f*x)); }

// ---- dtype-flexible accessors (f=1: float32 storage, f=0: bf16 storage) ----
__device__ __forceinline__ float ldf(const void* b, long i, int f) {
  return f ? ((const float*)b)[i] : (float)((const bf16*)b)[i];
}
__device__ __forceinline__ bf16x8 ldx8(const void* b, long i, int f) {
  if (f) {
    f32x4 a = *(const f32x4*)((const float*)b + i);
    f32x4 c = *(const f32x4*)((const float*)b + i + 4);
    bf16x8 r;
    r[0]=(bf16)a[0]; r[1]=(bf16)a[1]; r[2]=(bf16)a[2]; r[3]=(bf16)a[3];
    r[4]=(bf16)c[0]; r[5]=(bf16)c[1]; r[6]=(bf16)c[2]; r[7]=(bf16)c[3];
    return r;
  }
  return *(const bf16x8*)((const bf16*)b + i);
}
__device__ __forceinline__ f32x4 ld4f(const void* b, long i, int f) {
  if (f) return *(const f32x4*)((const float*)b + i);
  bf16x4 t = *(const bf16x4*)((const bf16*)b + i);
  f32x4 r; r[0]=(float)t[0]; r[1]=(float)t[1]; r[2]=(float)t[2]; r[3]=(float)t[3]; return r;
}
__device__ __forceinline__ void st4(void* b, long i, int f, f32x4 v) {
  if (f) *(f32x4*)((float*)b + i) = v;
  else   *(bf16x4*)((bf16*)b + i) = b4(v);
}

// ---------------------------------------------------------------------------
// One GRU scan step: D[gate][seq] = U x hT + W x xT (+bias via acc init),
// elementwise, write new h (transposed) to hout. NT = number of 16-seq tiles.
// ---------------------------------------------------------------------------
template<int NT>
__device__ __forceinline__ void gru_step(
    const bf16x8 (&AU)[3][4], const bf16x8 (&AW)[3][4],
    const f32x4& zb, const f32x4& rb, const f32x4& nbx, const f32x4& nbh,
    const bf16 (* __restrict__ hbuf)[136], const bf16 (* __restrict__ xbuf)[136],
    int l15, int quad, int gc,
    f32x4 (&h)[NT], bf16 (*hout)[136])
{
  f32x4 aZ[NT], aR[NT], aNx[NT], aNh[NT];
#pragma unroll
  for (int nt = 0; nt < NT; nt++) { aZ[nt]=zb; aR[nt]=rb; aNx[nt]=nbx; aNh[nt]=nbh; }
#pragma unroll
  for (int kt = 0; kt < 4; kt++) {
    bf16x8 Bh[NT], Bx[NT];
#pragma unroll
    for (int nt = 0; nt < NT; nt++) {
      Bh[nt] = *(const bf16x8*)&hbuf[nt*16 + l15][kt*32 + quad*8];
      Bx[nt] = *(const bf16x8*)&xbuf[nt*16 + l15][kt*32 + quad*8];
    }
#pragma unroll
    for (int nt = 0; nt < NT; nt++) {
      aZ[nt]  = mfma16(AU[0][kt], Bh[nt], aZ[nt]);
      aZ[nt]  = mfma16(AW[0][kt], Bx[nt], aZ[nt]);
      aR[nt]  = mfma16(AU[1][kt], Bh[nt], aR[nt]);
      aR[nt]  = mfma16(AW[1][kt], Bx[nt], aR[nt]);
      aNh[nt] = mfma16(AU[2][kt], Bh[nt], aNh[nt]);
      aNx[nt] = mfma16(AW[2][kt], Bx[nt], aNx[nt]);
    }
  }
#pragma unroll
  for (int nt = 0; nt < NT; nt++) {
    f32x4 hn = h[nt];
#pragma unroll
    for (int i = 0; i < 4; i++) {
      float z = sigm(aZ[nt][i]);
      float r = sigm(aR[nt][i]);
      float n = tanh_(aNx[nt][i] + r*aNh[nt][i]);
      hn[i] = z*hn[i] + (1.f - z)*n;
    }
    h[nt] = hn;
    *(bf16x4*)&hout[nt*16 + l15][gc] = b4(hn);
  }
}

// ---------------------------------------------------------------------------
// Fused per-level kernel (mode 0): 256 blocks x 512 thr, 32 classes/block.
//   Phase A: fn GRU (2 passes x 64 seqs, NT=4) + fe epilogue -> memfn + feT(LDS)
//   Phase B: member GRU (32 seqs, T=13; steps 9-12 read feT directly)
//   Phase C: super GRU (32 seqs, T=5; step 4 = m from registers) -> table + shadow
// mode 1 (glob): phase A only, 1 pass x 64 seqs, direct seq indexing.
//
// Register budget: LDS=102KB -> exactly 1 block/CU -> 2 waves/SIMD -> the full
// 256-VGPR/wave envelope is free. Rounds 1-2 showed the backend capping at 128
// VGPRs anyway (occupancy heuristic) -> ~96MB scratch spill per dispatch.
// amdgpu_waves_per_eu(1,2) states the achievable occupancy explicitly so the
// allocator can use up to 256. All t-loops are fully unrolled so the index
// arrays (rA/rM/rS) stay in registers (runtime-indexed arrays -> scratch).
// ---------------------------------------------------------------------------
__global__ __attribute__((amdgpu_flat_work_group_size(512, 512), amdgpu_waves_per_eu(1, 2)))
void level_kernel(
    const bf16* __restrict__ pUt, const bf16* __restrict__ pWt, const float* __restrict__ b2p,
    const bf16* __restrict__ wtT,
    const bf16* __restrict__ mUt, const bf16* __restrict__ mWt, const float* __restrict__ b2m,
    const bf16* __restrict__ sUt, const bf16* __restrict__ sWt, const float* __restrict__ b2s,
    const void* __restrict__ empty_params, const void* __restrict__ empty_members,
    const void* __restrict__ tabR, int tabRf,        // gather source (shadow bf16, or f32 table fallback)
    const int* __restrict__ fpi, const int* __restrict__ fri,
    const int* __restrict__ ppi, const int* __restrict__ spi,
    void* __restrict__ out, long memfnEB, long tabEB,
    bf16* __restrict__ shadowW,                      // shadow write base for this level's rows (may be null)
    const int* __restrict__ flagp, int mode)
{
  __shared__ __align__(16) bf16 hT[2][64][136];
  __shared__ __align__(16) bf16 xT[2][64][136];
  __shared__ __align__(16) bf16 feT[4][32][136];

  const int isf32 = *flagp;
  const int rf = (tabRf < 0) ? isf32 : tabRf;
  const int tid = threadIdx.x;
  const int w = tid >> 6;
  const int l15 = tid & 15;
  const int quad = (tid & 63) >> 4;
  const int gc = w*16 + quad*4;
  const int prow = tid >> 4;          // 0..31
  const int pc8 = (tid & 15) * 8;
  const int c0 = blockIdx.x * 32;

  bf16x8 AU[3][4], AW[3][4];
  f32x4 zb, rb, nbx, nbh;
  auto loadWB = [&](const bf16* Ut, const bf16* Wt, const float* b2) {
#pragma unroll
    for (int tr = 0; tr < 3; tr++)
#pragma unroll
      for (int kt = 0; kt < 4; kt++) {
        size_t o = (size_t)(tr*128 + w*16 + l15)*128 + kt*32 + quad*8;
        AU[tr][kt] = *(const bf16x8*)&Ut[o];
        AW[tr][kt] = *(const bf16x8*)&Wt[o];
      }
    zb  = *(const f32x4*)&b2[0*128 + gc];
    rb  = *(const f32x4*)&b2[1*128 + gc];
    nbx = *(const f32x4*)&b2[2*128 + gc];
    nbh = *(const f32x4*)&b2[3*128 + gc];
  };

  f32x4 hm[2];   // member result, carried into super phase

  // ================= Phase A: fn GRU + fe =================
  loadWB(pUt, pWt, b2p);
  const int npass = mode ? 1 : 2;
  for (int p = 0; p < npass; p++) {
    long sA[2]; int rA[2][4];
#pragma unroll
    for (int r = 0; r < 2; r++) {
      long s = mode ? ((long)blockIdx.x*64 + prow + 32*r)
                    : ((long)(c0 + prow)*4 + 2*p + r);
      sA[r] = s;
      int4 pi = *(const int4*)&fpi[s*4];
      rA[r][0]=pi.x; rA[r][1]=pi.y; rA[r][2]=pi.z; rA[r][3]=pi.w;
    }
    for (int i = tid; i < 64*136/2; i += 512) ((int*)hT)[i] = 0;
    { bf16x8 e = ldx8(empty_params, pc8, isf32);
      *(bf16x8*)&xT[0][prow][pc8]      = e;
      *(bf16x8*)&xT[0][prow + 32][pc8] = e; }
    __syncthreads();

    f32x4 h[4];
#pragma unroll
    for (int nt = 0; nt < 4; nt++) { h[nt][0]=0.f; h[nt][1]=0.f; h[nt][2]=0.f; h[nt][3]=0.f; }
    int buf = 0;
#pragma unroll
    for (int t = 0; t < 5; t++) {
      bf16x8 xn[2];
      if (t < 4) {
#pragma unroll
        for (int r = 0; r < 2; r++) xn[r] = ldx8(tabR, (long)rA[r][t]*128 + pc8, rf);
      }
      gru_step<4>(AU, AW, zb, rb, nbx, nbh,
                  (const bf16(*)[136])hT[buf], (const bf16(*)[136])xT[t&1],
                  l15, quad, gc, h, hT[1-buf]);
      if (t < 4) {
#pragma unroll
        for (int r = 0; r < 2; r++) *(bf16x8*)&xT[(t+1)&1][prow + 32*r][pc8] = xn[r];
      }
      __syncthreads();
      buf ^= 1;
    }
    // stage ret rows (transposed) into xT[0]
#pragma unroll
    for (int r = 0; r < 2; r++) {
      int ridx = fri[sA[r]];
      bf16x8 rv = ldx8(tabR, (long)ridx*128 + pc8, rf);
      *(bf16x8*)&xT[0][prow + 32*r][pc8] = rv;
    }
    __syncthreads();

    // fe GEMM: out = [h | ret] @ W_fn  (K=256)
    f32x4 acc[4];
#pragma unroll
    for (int nt = 0; nt < 4; nt++) { acc[nt][0]=0.f; acc[nt][1]=0.f; acc[nt][2]=0.f; acc[nt][3]=0.f; }
#pragma unroll
    for (int kt = 0; kt < 8; kt++) {
      bf16x8 A = *(const bf16x8*)&wtT[(size_t)(w*16 + l15)*256 + kt*32 + quad*8];
#pragma unroll
      for (int nt = 0; nt < 4; nt++) {
        bf16x8 B = (kt < 4) ? *(const bf16x8*)&hT[buf][nt*16 + l15][kt*32 + quad*8]
                            : *(const bf16x8*)&xT[0][nt*16 + l15][(kt-4)*32 + quad*8];
        acc[nt] = mfma16(A, B, acc[nt]);
      }
    }
#pragma unroll
    for (int nt = 0; nt < 4; nt++) {
      long s = mode ? ((long)blockIdx.x*64 + nt*16 + l15)
                    : ((long)(c0 + (nt&1)*16 + l15)*4 + 2*p + (nt>>1));
      st4(out, memfnEB + s*128 + gc, isf32, acc[nt]);
      if (!mode) *(bf16x4*)&feT[2*p + (nt>>1)][(nt&1)*16 + l15][gc] = b4(acc[nt]);
    }
    __syncthreads();
  }
  if (mode) return;

  // ================= Phase B: member GRU (T=13) =================
  loadWB(mUt, mWt, b2m);
  int rM[8];
  { int4 a = *(const int4*)&ppi[(size_t)(c0 + prow)*8];
    int4 b = *(const int4*)&ppi[(size_t)(c0 + prow)*8 + 4];
    rM[0]=a.x; rM[1]=a.y; rM[2]=a.z; rM[3]=a.w;
    rM[4]=b.x; rM[5]=b.y; rM[6]=b.z; rM[7]=b.w; }
  for (int i = tid; i < 32*136/2; i += 512) ((int*)hT)[i] = 0;
  { bf16x8 e = ldx8(empty_members, pc8, isf32);
    *(bf16x8*)&xT[0][prow][pc8] = e; }
  __syncthreads();

#pragma unroll
  for (int nt = 0; nt < 2; nt++) { hm[nt][0]=0.f; hm[nt][1]=0.f; hm[nt][2]=0.f; hm[nt][3]=0.f; }
  {
    int buf = 0;
#pragma unroll
    for (int t = 0; t < 13; t++) {
      bf16x8 xn;
      if (t < 8) xn = ldx8(tabR, (long)rM[t]*128 + pc8, rf);   // x for step t+1
      const bf16 (*xb)[136] = (t < 9) ? (const bf16(*)[136])xT[t&1]
                                      : (const bf16(*)[136])feT[t-9];
      gru_step<2>(AU, AW, zb, rb, nbx, nbh,
                  (const bf16(*)[136])hT[buf], xb, l15, quad, gc, hm, hT[1-buf]);
      if (t < 8) *(bf16x8*)&xT[(t+1)&1][prow][pc8] = xn;
      __syncthreads();
      buf ^= 1;
    }
  }

  // ================= Phase C: super GRU (T=5) =================
  loadWB(sUt, sWt, b2s);
  int rS[4];
  { int4 a = *(const int4*)&spi[(size_t)(c0 + prow)*4];
    rS[0]=a.x; rS[1]=a.y; rS[2]=a.z; rS[3]=a.w; }
  for (int i = tid; i < 32*136/2; i += 512) ((int*)hT)[i] = 0;
  { bf16x8 x0 = ldx8(tabR, (long)rS[0]*128 + pc8, rf);
    *(bf16x8*)&xT[0][prow][pc8] = x0; }
  __syncthreads();

  f32x4 hs[2];
#pragma unroll
  for (int nt = 0; nt < 2; nt++) { hs[nt][0]=0.f; hs[nt][1]=0.f; hs[nt][2]=0.f; hs[nt][3]=0.f; }
  {
    int buf = 0;
#pragma unroll
    for (int t = 0; t < 5; t++) {
      bf16x8 xn;
      if (t < 3) xn = ldx8(tabR, (long)rS[t+1]*128 + pc8, rf);
      gru_step<2>(AU, AW, zb, rb, nbx, nbh,
                  (const bf16(*)[136])hT[buf], (const bf16(*)[136])xT[t&1],
                  l15, quad, gc, hs, hT[1-buf]);
      if (t < 3) *(bf16x8*)&xT[(t+1)&1][prow][pc8] = xn;
      else if (t == 3) {   // stage m (registers) as x for step 4
#pragma unroll
        for (int nt = 0; nt < 2; nt++) *(bf16x4*)&xT[0][nt*16 + l15][gc] = b4(hm[nt]);
      }
      __syncthreads();
      buf ^= 1;
    }
  }
#pragma unroll
  for (int nt = 0; nt < 2; nt++) {
    long row = (long)(c0 + nt*16 + l15);
    st4(out, tabEB + row*128 + gc, isf32, hs[nt]);
    if (shadowW) *(bf16x4*)&shadowW[row*128 + gc] = b4(hs[nt]);
  }
}

// ---------------------------------------------------------------------------
// dtype detect: bf16-interpret first 128 u16 of basic_emb; any exponent>=128
// (|v|>=2) is impossible for genuine bf16 data here -> storage is float32.
// ---------------------------------------------------------------------------
__global__ void detect_kernel(const void* be, int* flag) {
  if (threadIdx.x == 0 && blockIdx.x == 0) {
    const unsigned short* u = (const unsigned short*)be;
    int f = 0;
    for (int i = 0; i < 128; i++) {
      unsigned e = (u[i] >> 7) & 0xFF;
      if (e >= 128) f = 1;
    }
    *flag = f;
  }
}

__global__ void convert_kernel(const void* pW, const void* pU, const void* mW, const void* mU,
                               const void* sW, const void* sU, const void* W_fn,
                               const void* pb, const void* mb, const void* sb,
                               bf16* pWt, bf16* pUt, bf16* mWt, bf16* mUt,
                               bf16* sWt, bf16* sUt, bf16* wtT,
                               float* b2p, float* b2m, float* b2s,
                               const int* flagp) {
  const int f = *flagp;
  int i = blockIdx.x*256 + threadIdx.x;
  const int TT = 384*128;
  if (i < 6*TT) {
    int which = i / TT, j = i - which*TT;
    int c = j >> 7, k = j & 127;
    const void* src = (which==0)?pW:(which==1)?pU:(which==2)?mW:(which==3)?mU:(which==4)?sW:sU;
    bf16* dst = (which==0)?pWt:(which==1)?pUt:(which==2)?mWt:(which==3)?mUt:(which==4)?sWt:sUt;
    dst[c*128 + k] = (bf16)ldf(src, (long)k*384 + c, f);
    return;
  }
  i -= 6*TT;
  if (i < 128*256) { int c = i >> 8, k = i & 255; wtT[c*256 + k] = (bf16)ldf(W_fn, (long)k*128 + c, f); return; }
  i -= 128*256;
  if (i < 3*512) {
    int which = i >> 9, j = i & 511;
    const void* b = (which==0)?pb:(which==1)?mb:sb;
    float* dst = (which==0)?b2p:(which==1)?b2m:b2s;
    int g = j >> 7, cc = j & 127;
    float v;
    if (g == 0)      v = ldf(b, cc, f)       + ldf(b, 384 + cc, f);
    else if (g == 1) v = ldf(b, 128 + cc, f) + ldf(b, 512 + cc, f);
    else if (g == 2) v = ldf(b, 256 + cc, f);
    else             v = ldf(b, 640 + cc, f);
    dst[j] = v;
  }
}

__global__ void level0_kernel(const int* __restrict__ basic_ids, const void* basic_emb,
                              void* out, bf16* __restrict__ shadow,
                              const int* __restrict__ flagp) {
  const int f = *flagp;
  int i = blockIdx.x*256 + threadIdx.x;   // < C*32
  int row = i >> 5, c4 = (i & 31) * 4;
  f32x4 v = ld4f(basic_emb, (long)basic_ids[row]*128 + c4, f);
  st4(out, (long)row*128 + c4, f, v);
  if (shadow) *(bf16x4*)&shadow[(long)row*128 + c4] = b4(v);
}

// ---------------------------------------------------------------------------
extern "C" void kernel_launch(void* const* d_in, const int* in_sizes, int n_in,
                              void* d_out, int out_size, void* d_ws, size_t ws_size,
                              hipStream_t stream) {
  const int* basic_ids      = (const int*)d_in[0];
  const int* prop_idx       = (const int*)d_in[1];
  const int* func_param_idx = (const int*)d_in[2];
  const int* func_ret_idx   = (const int*)d_in[3];
  const int* super_idx      = (const int*)d_in[4];
  const int* glob_param_idx = (const int*)d_in[5];
  const int* glob_ret_idx   = (const int*)d_in[6];
  const void* basic_emb     = d_in[7];
  const void* empty_params  = d_in[8];
  const void* empty_members = d_in[9];
  const void* W_fn = d_in[10];
  const void* pW = d_in[11]; const void* pU = d_in[12]; const void* pb = d_in[13];
  const void* mW = d_in[14]; const void* mU = d_in[15]; const void* mb = d_in[16];
  const void* sW = d_in[17]; const void* sU = d_in[18]; const void* sb = d_in[19];

  // d_out element layout: table [NTOT*128] | glob [NF*128] | memfn [7*C*F*128]
  const long GB = (long)NTOT*128;
  const long MB0 = GB + (long)NF*128;
  auto FEB = [&](int l) { return MB0 + (long)(l-1)*C*F*128; };

  char* wp = (char*)d_ws;
  auto carve = [&](size_t bytes) { char* p = wp; wp += (bytes + 255) & ~(size_t)255; return p; };
  int*  flag = (int*)carve(256);
  bf16* pWt = (bf16*)carve(384*128*2);
  bf16* pUt = (bf16*)carve(384*128*2);
  bf16* mWt = (bf16*)carve(384*128*2);
  bf16* mUt = (bf16*)carve(384*128*2);
  bf16* sWt = (bf16*)carve(384*128*2);
  bf16* sUt = (bf16*)carve(384*128*2);
  bf16* wtT = (bf16*)carve(128*256*2);
  float* b2p = (float*)carve(512*4);
  float* b2m = (float*)carve(512*4);
  float* b2s = (float*)carve(512*4);
  bf16* shadow = (bf16*)carve((size_t)NTOT*128*2);   // bf16 mirror of table, ~16.8 MB

  const bool useShadow = ((size_t)(wp - (char*)d_ws) <= ws_size);
  const void* tabR = useShadow ? (const void*)shadow : (const void*)d_out;
  const int tabRf  = useShadow ? 0 : -1;             // -1: use detected dtype flag
  bf16* shadowL0   = useShadow ? shadow : (bf16*)nullptr;

  detect_kernel<<<1, 64, 0, stream>>>(basic_emb, flag);
  {
    int total = 6*384*128 + 128*256 + 3*512;
    convert_kernel<<<(total + 255)/256, 256, 0, stream>>>(pW, pU, mW, mU, sW, sU, W_fn,
                                                          pb, mb, sb,
                                                          pWt, pUt, mWt, mUt, sWt, sUt, wtT,
                                                          b2p, b2m, b2s, flag);
  }
  level0_kernel<<<(C*32)/256, 256, 0, stream>>>(basic_ids, basic_emb, d_out, shadowL0, flag);

  for (int l = 1; l < LVL; l++) {
    level_kernel<<<C/32, 512, 0, stream>>>(
        pUt, pWt, b2p, wtT, mUt, mWt, b2m, sUt, sWt, b2s,
        empty_params, empty_members,
        tabR, tabRf,
        func_param_idx + (size_t)(l-1)*C*F*K,
        func_ret_idx   + (size_t)(l-1)*C*F,
        prop_idx       + (size_t)(l-1)*C*P,
        super_idx      + (size_t)(l-1)*C*S,
        d_out, FEB(l), (long)l*C*128,
        useShadow ? shadow + (size_t)l*C*128 : (bf16*)nullptr,
        flag, 0);
  }

  // global functions (NF seqs, T=5, 1 pass of 64 seqs/block) -> glob
  level_kernel<<<NF/64, 512, 0, stream>>>(
      pUt, pWt, b2p, wtT, mUt, mWt, b2m, sUt, sWt, b2s,
      empty_params, empty_members,
      tabR, tabRf,
      glob_param_idx, glob_ret_idx, nullptr, nullptr,
      d_out, GB, 0, (bf16*)nullptr,
      flag, 1);
}

// Round 5
// 798.853 us; speedup vs baseline: 1.4011x; 1.3540x over previous
//
#include <hip/hip_runtime.h>

#define LVL 8
#define C 8192
#define D 128
#define P 8
#define F 4
#define K 4
#define S 4
#define NF 16384
#define NTOT (LVL*C)   // 65536

typedef __bf16 bf16;
typedef bf16 bf16x4 __attribute__((ext_vector_type(4)));
typedef bf16 bf16x8 __attribute__((ext_vector_type(8)));
typedef float f32x4 __attribute__((ext_vector_type(4)));

__device__ __forceinline__ f32x4 mfma16(bf16x8 a, bf16x8 b, f32x4 c) {
  return __builtin_amdgcn_mfma_f32_16x16x32_bf16(a, b, c, 0, 0, 0);
}
__device__ __forceinline__ bf16x4 b4(f32x4 v) {
  bf16x4 r; r[0]=(bf16)v[0]; r[1]=(bf16)v[1]; r[2]=(bf16)v[2]; r[3]=(bf16)v[3]; return r;
}
__device__ __forceinline__ float sigm(float x) { return __builtin_amdgcn_rcpf(1.f + __expf(-x)); }
__device__ __forceinline__ float tanh_(float x) { return 1.f - 2.f*__builtin_amdgcn_rcpf(1.f + __expf(2.f*x)); }

// ---- dtype-flexible accessors (f=1: float32 storage, f=0: bf16 storage) ----
__device__ __forceinline__ float ldf(const void* b, long i, int f) {
  return f ? ((const float*)b)[i] : (float)((const bf16*)b)[i];
}
__device__ __forceinline__ bf16x8 ldx8(const void* b, long i, int f) {
  if (f) {
    f32x4 a = *(const f32x4*)((const float*)b + i);
    f32x4 c = *(const f32x4*)((const float*)b + i + 4);
    bf16x8 r;
    r[0]=(bf16)a[0]; r[1]=(bf16)a[1]; r[2]=(bf16)a[2]; r[3]=(bf16)a[3];
    r[4]=(bf16)c[0]; r[5]=(bf16)c[1]; r[6]=(bf16)c[2]; r[7]=(bf16)c[3];
    return r;
  }
  return *(const bf16x8*)((const bf16*)b + i);
}
__device__ __forceinline__ f32x4 ld4f(const void* b, long i, int f) {
  if (f) return *(const f32x4*)((const float*)b + i);
  bf16x4 t = *(const bf16x4*)((const bf16*)b + i);
  f32x4 r; r[0]=(float)t[0]; r[1]=(float)t[1]; r[2]=(float)t[2]; r[3]=(float)t[3]; return r;
}
__device__ __forceinline__ void st4(void* b, long i, int f, f32x4 v) {
  if (f) *(f32x4*)((float*)b + i) = v;
  else   *(bf16x4*)((bf16*)b + i) = b4(v);
}

// ---------------------------------------------------------------------------
// One GRU scan step: D[gatecol][seq] = U x hT + W x xT (+bias via acc init),
// elementwise, write new h (transposed) to hout. NT = number of 16-seq tiles.
// NT=2 ONLY: keeps kt-loop peak live set ~195 regs (96 weight + 32 acc +
// 16 B-frag + h/bias/addr), inside the 128V+128A unified envelope -> no
// scratch. NT=4 (rounds 0-3) peaked ~270 -> scratch spill (~96 MB/dispatch).
// ---------------------------------------------------------------------------
template<int NT>
__device__ __forceinline__ void gru_step(
    const bf16x8 (&AU)[3][4], const bf16x8 (&AW)[3][4],
    const f32x4& zb, const f32x4& rb, const f32x4& nbx, const f32x4& nbh,
    const bf16 (* __restrict__ hbuf)[136], const bf16 (* __restrict__ xbuf)[136],
    int l15, int quad, int gc,
    f32x4 (&h)[NT], bf16 (*hout)[136])
{
  f32x4 aZ[NT], aR[NT], aNx[NT], aNh[NT];
#pragma unroll
  for (int nt = 0; nt < NT; nt++) { aZ[nt]=zb; aR[nt]=rb; aNx[nt]=nbx; aNh[nt]=nbh; }
#pragma unroll
  for (int kt = 0; kt < 4; kt++) {
    bf16x8 Bh[NT], Bx[NT];
#pragma unroll
    for (int nt = 0; nt < NT; nt++) {
      Bh[nt] = *(const bf16x8*)&hbuf[nt*16 + l15][kt*32 + quad*8];
      Bx[nt] = *(const bf16x8*)&xbuf[nt*16 + l15][kt*32 + quad*8];
    }
#pragma unroll
    for (int nt = 0; nt < NT; nt++) {
      aZ[nt]  = mfma16(AU[0][kt], Bh[nt], aZ[nt]);
      aZ[nt]  = mfma16(AW[0][kt], Bx[nt], aZ[nt]);
      aR[nt]  = mfma16(AU[1][kt], Bh[nt], aR[nt]);
      aR[nt]  = mfma16(AW[1][kt], Bx[nt], aR[nt]);
      aNh[nt] = mfma16(AU[2][kt], Bh[nt], aNh[nt]);
      aNx[nt] = mfma16(AW[2][kt], Bx[nt], aNx[nt]);
    }
  }
#pragma unroll
  for (int nt = 0; nt < NT; nt++) {
    f32x4 hn = h[nt];
#pragma unroll
    for (int i = 0; i < 4; i++) {
      float z = sigm(aZ[nt][i]);
      float r = sigm(aR[nt][i]);
      float n = tanh_(aNx[nt][i] + r*aNh[nt][i]);
      hn[i] = z*hn[i] + (1.f - z)*n;
    }
    h[nt] = hn;
    *(bf16x4*)&hout[nt*16 + l15][gc] = b4(hn);
  }
}

// ---------------------------------------------------------------------------
// Fused per-level kernel (mode 0): 256 blocks x 512 thr, 32 classes/block.
//   Phase A: fn GRU (4 passes x 32 seqs, NT=2) + fe epilogue -> memfn + feT(LDS)
//   Phase B: member GRU (32 seqs, T=13; steps 9-12 read feT directly)
//   Phase C: super GRU (32 seqs, T=5; step 4 = m from registers) -> table + shadow
// mode 1 (glob): phase A only, 1 pass x 32 seqs, direct seq indexing.
// All gathers read the bf16 shadow table (16 B/lane); 2-deep gather pipeline
// in every phase (issue row t+1 before step t's MFMAs, consume after).
// LDS 68 KB. Plain launch_bounds only (amdgpu_num_vgpr broke the r4 run).
// ---------------------------------------------------------------------------
__global__ __launch_bounds__(512, 1) void level_kernel(
    const bf16* __restrict__ pUt, const bf16* __restrict__ pWt, const float* __restrict__ b2p,
    const bf16* __restrict__ wtT,
    const bf16* __restrict__ mUt, const bf16* __restrict__ mWt, const float* __restrict__ b2m,
    const bf16* __restrict__ sUt, const bf16* __restrict__ sWt, const float* __restrict__ b2s,
    const void* __restrict__ empty_params, const void* __restrict__ empty_members,
    const void* __restrict__ tabR, int tabRf,        // gather source (shadow bf16, or f32 table fallback)
    const int* __restrict__ fpi, const int* __restrict__ fri,
    const int* __restrict__ ppi, const int* __restrict__ spi,
    void* __restrict__ out, long memfnEB, long tabEB,
    bf16* __restrict__ shadowW,                      // shadow write base for this level's rows (may be null)
    const int* __restrict__ flagp, int mode)
{
  __shared__ __align__(16) bf16 hT[2][32][136];
  __shared__ __align__(16) bf16 xT[2][32][136];
  __shared__ __align__(16) bf16 feT[4][32][136];

  const int isf32 = *flagp;
  const int rf = (tabRf < 0) ? isf32 : tabRf;
  const int tid = threadIdx.x;
  const int w = tid >> 6;
  const int l15 = tid & 15;
  const int quad = (tid & 63) >> 4;
  const int gc = w*16 + quad*4;
  const int prow = tid >> 4;          // 0..31
  const int pc8 = (tid & 15) * 8;
  const int c0 = blockIdx.x * 32;

  bf16x8 AU[3][4], AW[3][4];
  f32x4 zb, rb, nbx, nbh;
  auto loadWB = [&](const bf16* Ut, const bf16* Wt, const float* b2) {
#pragma unroll
    for (int tr = 0; tr < 3; tr++)
#pragma unroll
      for (int kt = 0; kt < 4; kt++) {
        size_t o = (size_t)(tr*128 + w*16 + l15)*128 + kt*32 + quad*8;
        AU[tr][kt] = *(const bf16x8*)&Ut[o];
        AW[tr][kt] = *(const bf16x8*)&Wt[o];
      }
    zb  = *(const f32x4*)&b2[0*128 + gc];
    rb  = *(const f32x4*)&b2[1*128 + gc];
    nbx = *(const f32x4*)&b2[2*128 + gc];
    nbh = *(const f32x4*)&b2[3*128 + gc];
  };

  f32x4 hm[2];   // member result, carried into super phase

  // ================= Phase A: fn GRU + fe (NT=2, 32 seqs/pass) ==============
  loadWB(pUt, pWt, b2p);
  const int npass = mode ? 1 : 4;
  for (int p = 0; p < npass; p++) {
    // pass p covers fn index p of each of the block's 32 classes (mode 0)
    long s = mode ? ((long)blockIdx.x*32 + prow)
                  : ((long)(c0 + prow)*4 + p);
    int rA[4];
    { int4 pi = *(const int4*)&fpi[s*4];
      rA[0]=pi.x; rA[1]=pi.y; rA[2]=pi.z; rA[3]=pi.w; }
    bf16x8 pend0 = ldx8(tabR, (long)rA[0]*128 + pc8, rf);
    bf16x8 pend1;
    for (int i = tid; i < 32*136/2; i += 512) ((int*)hT)[i] = 0;
    { bf16x8 e = ldx8(empty_params, pc8, isf32);
      *(bf16x8*)&xT[0][prow][pc8] = e; }
    __syncthreads();

    f32x4 h[2];
#pragma unroll
    for (int nt = 0; nt < 2; nt++) { h[nt][0]=0.f; h[nt][1]=0.f; h[nt][2]=0.f; h[nt][3]=0.f; }
    int buf = 0;
#pragma unroll
    for (int t = 0; t < 5; t++) {
      if (t + 1 < 4) pend1 = ldx8(tabR, (long)rA[t+1]*128 + pc8, rf);  // issue L_{t+1}
      gru_step<2>(AU, AW, zb, rb, nbx, nbh,
                  (const bf16(*)[136])hT[buf], (const bf16(*)[136])xT[t&1],
                  l15, quad, gc, h, hT[1-buf]);
      if (t < 4) { *(bf16x8*)&xT[(t+1)&1][prow][pc8] = pend0; pend0 = pend1; }  // consume L_t
      __syncthreads();
      buf ^= 1;
    }
    // stage ret row (transposed) into xT[0]
    { int ridx = fri[s];
      bf16x8 rv = ldx8(tabR, (long)ridx*128 + pc8, rf);
      *(bf16x8*)&xT[0][prow][pc8] = rv; }
    __syncthreads();

    // fe GEMM: out = [h | ret] @ W_fn  (K=256); final hT is in hT[buf]
    f32x4 acc[2];
#pragma unroll
    for (int nt = 0; nt < 2; nt++) { acc[nt][0]=0.f; acc[nt][1]=0.f; acc[nt][2]=0.f; acc[nt][3]=0.f; }
#pragma unroll
    for (int kt = 0; kt < 8; kt++) {
      bf16x8 A = *(const bf16x8*)&wtT[(size_t)(w*16 + l15)*256 + kt*32 + quad*8];
#pragma unroll
      for (int nt = 0; nt < 2; nt++) {
        bf16x8 B = (kt < 4) ? *(const bf16x8*)&hT[buf][nt*16 + l15][kt*32 + quad*8]
                            : *(const bf16x8*)&xT[0][nt*16 + l15][(kt-4)*32 + quad*8];
        acc[nt] = mfma16(A, B, acc[nt]);
      }
    }
#pragma unroll
    for (int nt = 0; nt < 2; nt++) {
      long so = mode ? ((long)blockIdx.x*32 + nt*16 + l15)
                     : ((long)(c0 + nt*16 + l15)*4 + p);
      st4(out, memfnEB + so*128 + gc, isf32, acc[nt]);
      if (!mode) *(bf16x4*)&feT[p][nt*16 + l15][gc] = b4(acc[nt]);
    }
    __syncthreads();   // protect xT/hT/feT before next pass / phase B
  }
  if (mode) return;

  // ================= Phase B: member GRU (T=13), 2-deep gather pipe =========
  loadWB(mUt, mWt, b2m);
  int rM[8];
  { int4 a = *(const int4*)&ppi[(size_t)(c0 + prow)*8];
    int4 b = *(const int4*)&ppi[(size_t)(c0 + prow)*8 + 4];
    rM[0]=a.x; rM[1]=a.y; rM[2]=a.z; rM[3]=a.w;
    rM[4]=b.x; rM[5]=b.y; rM[6]=b.z; rM[7]=b.w; }
  // L_k = x for step k+1 (row rM[k]), k=0..7. Issue L_0 before the barrier.
  bf16x8 pend0 = ldx8(tabR, (long)rM[0]*128 + pc8, rf);
  bf16x8 pend1;
  for (int i = tid; i < 32*136/2; i += 512) ((int*)hT)[i] = 0;
  { bf16x8 e = ldx8(empty_members, pc8, isf32);
    *(bf16x8*)&xT[0][prow][pc8] = e; }
  __syncthreads();

#pragma unroll
  for (int nt = 0; nt < 2; nt++) { hm[nt][0]=0.f; hm[nt][1]=0.f; hm[nt][2]=0.f; hm[nt][3]=0.f; }
  {
    int buf = 0;
#pragma unroll
    for (int t = 0; t < 13; t++) {
      if (t + 1 < 8) pend1 = ldx8(tabR, (long)rM[t+1]*128 + pc8, rf);  // issue L_{t+1}
      const bf16 (*xb)[136] = (t < 9) ? (const bf16(*)[136])xT[t&1]
                                      : (const bf16(*)[136])feT[t-9];
      gru_step<2>(AU, AW, zb, rb, nbx, nbh,
                  (const bf16(*)[136])hT[buf], xb, l15, quad, gc, hm, hT[1-buf]);
      if (t < 8) { *(bf16x8*)&xT[(t+1)&1][prow][pc8] = pend0; pend0 = pend1; }  // consume L_t
      __syncthreads();
      buf ^= 1;
    }
  }

  // ================= Phase C: super GRU (T=5), 2-deep gather pipe ===========
  loadWB(sUt, sWt, b2s);
  int rS[4];
  { int4 a = *(const int4*)&spi[(size_t)(c0 + prow)*4];
    rS[0]=a.x; rS[1]=a.y; rS[2]=a.z; rS[3]=a.w; }
  // L_k = x for step k+1 (row rS[k+1]), k=0..2. Issue L_0 before the barrier.
  pend0 = ldx8(tabR, (long)rS[1]*128 + pc8, rf);
  for (int i = tid; i < 32*136/2; i += 512) ((int*)hT)[i] = 0;
  { bf16x8 x0 = ldx8(tabR, (long)rS[0]*128 + pc8, rf);
    *(bf16x8*)&xT[0][prow][pc8] = x0; }
  __syncthreads();

  f32x4 hs[2];
#pragma unroll
  for (int nt = 0; nt < 2; nt++) { hs[nt][0]=0.f; hs[nt][1]=0.f; hs[nt][2]=0.f; hs[nt][3]=0.f; }
  {
    int buf = 0;
#pragma unroll
    for (int t = 0; t < 5; t++) {
      if (t + 1 < 3) pend1 = ldx8(tabR, (long)rS[t+2]*128 + pc8, rf);  // issue L_{t+1}
      gru_step<2>(AU, AW, zb, rb, nbx, nbh,
                  (const bf16(*)[136])hT[buf], (const bf16(*)[136])xT[t&1],
                  l15, quad, gc, hs, hT[1-buf]);
      if (t < 3) { *(bf16x8*)&xT[(t+1)&1][prow][pc8] = pend0; pend0 = pend1; }  // consume L_t
      else if (t == 3) {   // stage m (registers) as x for step 4
#pragma unroll
        for (int nt = 0; nt < 2; nt++) *(bf16x4*)&xT[0][nt*16 + l15][gc] = b4(hm[nt]);
      }
      __syncthreads();
      buf ^= 1;
    }
  }
#pragma unroll
  for (int nt = 0; nt < 2; nt++) {
    long row = (long)(c0 + nt*16 + l15);
    st4(out, tabEB + row*128 + gc, isf32, hs[nt]);
    if (shadowW) *(bf16x4*)&shadowW[row*128 + gc] = b4(hs[nt]);
  }
}

// ---------------------------------------------------------------------------
// dtype detect: bf16-interpret first 128 u16 of basic_emb; any exponent>=128
// (|v|>=2) is impossible for genuine bf16 data here -> storage is float32.
// ---------------------------------------------------------------------------
__global__ void detect_kernel(const void* be, int* flag) {
  if (threadIdx.x == 0 && blockIdx.x == 0) {
    const unsigned short* u = (const unsigned short*)be;
    int f = 0;
    for (int i = 0; i < 128; i++) {
      unsigned e = (u[i] >> 7) & 0xFF;
      if (e >= 128) f = 1;
    }
    *flag = f;
  }
}

__global__ void convert_kernel(const void* pW, const void* pU, const void* mW, const void* mU,
                               const void* sW, const void* sU, const void* W_fn,
                               const void* pb, const void* mb, const void* sb,
                               bf16* pWt, bf16* pUt, bf16* mWt, bf16* mUt,
                               bf16* sWt, bf16* sUt, bf16* wtT,
                               float* b2p, float* b2m, float* b2s,
                               const int* flagp) {
  const int f = *flagp;
  int i = blockIdx.x*256 + threadIdx.x;
  const int TT = 384*128;
  if (i < 6*TT) {
    int which = i / TT, j = i - which*TT;
    int c = j >> 7, k = j & 127;
    const void* src = (which==0)?pW:(which==1)?pU:(which==2)?mW:(which==3)?mU:(which==4)?sW:sU;
    bf16* dst = (which==0)?pWt:(which==1)?pUt:(which==2)?mWt:(which==3)?mUt:(which==4)?sWt:sUt;
    dst[c*128 + k] = (bf16)ldf(src, (long)k*384 + c, f);
    return;
  }
  i -= 6*TT;
  if (i < 128*256) { int c = i >> 8, k = i & 255; wtT[c*256 + k] = (bf16)ldf(W_fn, (long)k*128 + c, f); return; }
  i -= 128*256;
  if (i < 3*512) {
    int which = i >> 9, j = i & 511;
    const void* b = (which==0)?pb:(which==1)?mb:sb;
    float* dst = (which==0)?b2p:(which==1)?b2m:b2s;
    int g = j >> 7, cc = j & 127;
    float v;
    if (g == 0)      v = ldf(b, cc, f)       + ldf(b, 384 + cc, f);
    else if (g == 1) v = ldf(b, 128 + cc, f) + ldf(b, 512 + cc, f);
    else if (g == 2) v = ldf(b, 256 + cc, f);
    else             v = ldf(b, 640 + cc, f);
    dst[j] = v;
  }
}

__global__ void level0_kernel(const int* __restrict__ basic_ids, const void* basic_emb,
                              void* out, bf16* __restrict__ shadow,
                              const int* __restrict__ flagp) {
  const int f = *flagp;
  int i = blockIdx.x*256 + threadIdx.x;   // < C*32
  int row = i >> 5, c4 = (i & 31) * 4;
  f32x4 v = ld4f(basic_emb, (long)basic_ids[row]*128 + c4, f);
  st4(out, (long)row*128 + c4, f, v);
  if (shadow) *(bf16x4*)&shadow[(long)row*128 + c4] = b4(v);
}

// ---------------------------------------------------------------------------
extern "C" void kernel_launch(void* const* d_in, const int* in_sizes, int n_in,
                              void* d_out, int out_size, void* d_ws, size_t ws_size,
                              hipStream_t stream) {
  const int* basic_ids      = (const int*)d_in[0];
  const int* prop_idx       = (const int*)d_in[1];
  const int* func_param_idx = (const int*)d_in[2];
  const int* func_ret_idx   = (const int*)d_in[3];
  const int* super_idx      = (const int*)d_in[4];
  const int* glob_param_idx = (const int*)d_in[5];
  const int* glob_ret_idx   = (const int*)d_in[6];
  const void* basic_emb     = d_in[7];
  const void* empty_params  = d_in[8];
  const void* empty_members = d_in[9];
  const void* W_fn = d_in[10];
  const void* pW = d_in[11]; const void* pU = d_in[12]; const void* pb = d_in[13];
  const void* mW = d_in[14]; const void* mU = d_in[15]; const void* mb = d_in[16];
  const void* sW = d_in[17]; const void* sU = d_in[18]; const void* sb = d_in[19];

  // d_out element layout: table [NTOT*128] | glob [NF*128] | memfn [7*C*F*128]
  const long GB = (long)NTOT*128;
  const long MB0 = GB + (long)NF*128;
  auto FEB = [&](int l) { return MB0 + (long)(l-1)*C*F*128; };

  char* wp = (char*)d_ws;
  auto carve = [&](size_t bytes) { char* p = wp; wp += (bytes + 255) & ~(size_t)255; return p; };
  int*  flag = (int*)carve(256);
  bf16* pWt = (bf16*)carve(384*128*2);
  bf16* pUt = (bf16*)carve(384*128*2);
  bf16* mWt = (bf16*)carve(384*128*2);
  bf16* mUt = (bf16*)carve(384*128*2);
  bf16* sWt = (bf16*)carve(384*128*2);
  bf16* sUt = (bf16*)carve(384*128*2);
  bf16* wtT = (bf16*)carve(128*256*2);
  float* b2p = (float*)carve(512*4);
  float* b2m = (float*)carve(512*4);
  float* b2s = (float*)carve(512*4);
  bf16* shadow = (bf16*)carve((size_t)NTOT*128*2);   // bf16 mirror of table, ~16.8 MB

  const bool useShadow = ((size_t)(wp - (char*)d_ws) <= ws_size);
  const void* tabR = useShadow ? (const void*)shadow : (const void*)d_out;
  const int tabRf  = useShadow ? 0 : -1;             // -1: use detected dtype flag
  bf16* shadowL0   = useShadow ? shadow : (bf16*)nullptr;

  detect_kernel<<<1, 64, 0, stream>>>(basic_emb, flag);
  {
    int total = 6*384*128 + 128*256 + 3*512;
    convert_kernel<<<(total + 255)/256, 256, 0, stream>>>(pW, pU, mW, mU, sW, sU, W_fn,
                                                          pb, mb, sb,
                                                          pWt, pUt, mWt, mUt, sWt, sUt, wtT,
                                                          b2p, b2m, b2s, flag);
  }
  level0_kernel<<<(C*32)/256, 256, 0, stream>>>(basic_ids, basic_emb, d_out, shadowL0, flag);

  for (int l = 1; l < LVL; l++) {
    level_kernel<<<C/32, 512, 0, stream>>>(
        pUt, pWt, b2p, wtT, mUt, mWt, b2m, sUt, sWt, b2s,
        empty_params, empty_members,
        tabR, tabRf,
        func_param_idx + (size_t)(l-1)*C*F*K,
        func_ret_idx   + (size_t)(l-1)*C*F,
        prop_idx       + (size_t)(l-1)*C*P,
        super_idx      + (size_t)(l-1)*C*S,
        d_out, FEB(l), (long)l*C*128,
        useShadow ? shadow + (size_t)l*C*128 : (bf16*)nullptr,
        flag, 0);
  }

  // global functions (NF seqs, T=5, 32 seqs/block) -> glob
  level_kernel<<<NF/32, 512, 0, stream>>>(
      pUt, pWt, b2p, wtT, mUt, mWt, b2m, sUt, sWt, b2s,
      empty_params, empty_members,
      tabR, tabRf,
      glob_param_idx, glob_ret_idx, nullptr, nullptr,
      d_out, GB, 0, (bf16*)nullptr,
      flag, 1);
}

// Round 7
// 781.621 us; speedup vs baseline: 1.4319x; 1.0220x over previous
//
#include <hip/hip_runtime.h>

#define LVL 8
#define C 8192
#define D 128
#define P 8
#define F 4
#define K 4
#define S 4
#define NF 16384
#define NTOT (LVL*C)   // 65536

typedef __bf16 bf16;
typedef bf16 bf16x4 __attribute__((ext_vector_type(4)));
typedef bf16 bf16x8 __attribute__((ext_vector_type(8)));
typedef float f32x4 __attribute__((ext_vector_type(4)));

__device__ __forceinline__ f32x4 mfma16(bf16x8 a, bf16x8 b, f32x4 c) {
  return __builtin_amdgcn_mfma_f32_16x16x32_bf16(a, b, c, 0, 0, 0);
}
__device__ __forceinline__ bf16x4 b4(f32x4 v) {
  bf16x4 r; r[0]=(bf16)v[0]; r[1]=(bf16)v[1]; r[2]=(bf16)v[2]; r[3]=(bf16)v[3]; return r;
}
__device__ __forceinline__ float sigm(float x) { return __builtin_amdgcn_rcpf(1.f + __expf(-x)); }
__device__ __forceinline__ float tanh_(float x) { return 1.f - 2.f*__builtin_amdgcn_rcpf(1.f + __expf(2.f*x)); }

// Non-draining barrier (T4 counted-vmcnt idea): drain LDS ops (lgkmcnt) so
// hT/xT writes are visible across the block, but leave global gather loads
// IN FLIGHT across the barrier. __syncthreads() emits s_waitcnt vmcnt(0)
// before s_barrier, forcing every GRU step to eat full L2-miss gather
// latency (~600-900 cy). Safe here: no global location gathered by this
// kernel is written by this kernel (topological DAG: gathers reference rows
// < l*C, written by PREVIOUS kernel launches; this kernel's outputs are only
// consumed by later launches). Single volatile asm with "memory" clobber =
// full compiler memory barrier + hw barrier, no reordering gap.
__device__ __forceinline__ void bar() {
  asm volatile("s_waitcnt lgkmcnt(0)\n\ts_barrier" ::: "memory");
}

// ---- dtype-flexible accessors (f=1: float32 storage, f=0: bf16 storage) ----
__device__ __forceinline__ float ldf(const void* b, long i, int f) {
  return f ? ((const float*)b)[i] : (float)((const bf16*)b)[i];
}
__device__ __forceinline__ bf16x8 ldx8(const void* b, long i, int f) {
  if (f) {
    f32x4 a = *(const f32x4*)((const float*)b + i);
    f32x4 c = *(const f32x4*)((const float*)b + i + 4);
    bf16x8 r;
    r[0]=(bf16)a[0]; r[1]=(bf16)a[1]; r[2]=(bf16)a[2]; r[3]=(bf16)a[3];
    r[4]=(bf16)c[0]; r[5]=(bf16)c[1]; r[6]=(bf16)c[2]; r[7]=(bf16)c[3];
    return r;
  }
  return *(const bf16x8*)((const bf16*)b + i);
}
__device__ __forceinline__ f32x4 ld4f(const void* b, long i, int f) {
  if (f) return *(const f32x4*)((const float*)b + i);
  bf16x4 t = *(const bf16x4*)((const bf16*)b + i);
  f32x4 r; r[0]=(float)t[0]; r[1]=(float)t[1]; r[2]=(float)t[2]; r[3]=(float)t[3]; return r;
}
__device__ __forceinline__ void st4(void* b, long i, int f, f32x4 v) {
  if (f) *(f32x4*)((float*)b + i) = v;
  else   *(bf16x4*)((bf16*)b + i) = b4(v);
}

// ---------------------------------------------------------------------------
// One GRU scan step. NT=2 only (reg envelope). SKIPU: t=0 peel — h0=0 means
// every U-MFMA yields exactly its C-operand (0-products add exact 0), so skip
// the U MFMAs and the hT reads entirely. Bit-identical to computing them.
// ---------------------------------------------------------------------------
template<int NT, bool SKIPU>
__device__ __forceinline__ void gru_step(
    const bf16x8 (&AU)[3][4], const bf16x8 (&AW)[3][4],
    const f32x4& zb, const f32x4& rb, const f32x4& nbx, const f32x4& nbh,
    const bf16 (* __restrict__ hbuf)[136], const bf16 (* __restrict__ xbuf)[136],
    int l15, int quad, int gc,
    f32x4 (&h)[NT], bf16 (*hout)[136])
{
  f32x4 aZ[NT], aR[NT], aNx[NT], aNh[NT];
#pragma unroll
  for (int nt = 0; nt < NT; nt++) { aZ[nt]=zb; aR[nt]=rb; aNx[nt]=nbx; aNh[nt]=nbh; }
#pragma unroll
  for (int kt = 0; kt < 4; kt++) {
    bf16x8 Bh[NT], Bx[NT];
#pragma unroll
    for (int nt = 0; nt < NT; nt++) {
      if (!SKIPU) Bh[nt] = *(const bf16x8*)&hbuf[nt*16 + l15][kt*32 + quad*8];
      Bx[nt] = *(const bf16x8*)&xbuf[nt*16 + l15][kt*32 + quad*8];
    }
#pragma unroll
    for (int nt = 0; nt < NT; nt++) {
      if (!SKIPU) aZ[nt]  = mfma16(AU[0][kt], Bh[nt], aZ[nt]);
      aZ[nt]  = mfma16(AW[0][kt], Bx[nt], aZ[nt]);
      if (!SKIPU) aR[nt]  = mfma16(AU[1][kt], Bh[nt], aR[nt]);
      aR[nt]  = mfma16(AW[1][kt], Bx[nt], aR[nt]);
      if (!SKIPU) aNh[nt] = mfma16(AU[2][kt], Bh[nt], aNh[nt]);
      aNx[nt] = mfma16(AW[2][kt], Bx[nt], aNx[nt]);
    }
  }
#pragma unroll
  for (int nt = 0; nt < NT; nt++) {
    f32x4 hn = h[nt];
#pragma unroll
    for (int i = 0; i < 4; i++) {
      float z = sigm(aZ[nt][i]);
      float r = sigm(aR[nt][i]);
      float n = tanh_(aNx[nt][i] + r*aNh[nt][i]);
      hn[i] = z*hn[i] + (1.f - z)*n;
    }
    h[nt] = hn;
    *(bf16x4*)&hout[nt*16 + l15][gc] = b4(hn);
  }
}

// ---------------------------------------------------------------------------
// Fused per-level kernel (mode 0): 256 blocks x 512 thr, 32 classes/block.
//   Phase A: fn GRU (4 passes x 32 seqs, NT=2) + fe epilogue -> memfn + feT(LDS)
//   Phase B: member GRU (32 seqs, T=13; steps 9-12 read feT directly)
//   Phase C: super GRU (32 seqs, T=5; step 4 = m from registers) -> table + shadow
// mode 1 (glob): phase A only, 1 pass x 32 seqs, direct seq indexing.
// Gathers read the bf16 shadow table; prefetched 2-deep and kept in flight
// across barriers via bar() (non-draining). t=0 peeled in every GRU.
// ---------------------------------------------------------------------------
__global__ __launch_bounds__(512, 1) void level_kernel(
    const bf16* __restrict__ pUt, const bf16* __restrict__ pWt, const float* __restrict__ b2p,
    const bf16* __restrict__ wtT,
    const bf16* __restrict__ mUt, const bf16* __restrict__ mWt, const float* __restrict__ b2m,
    const bf16* __restrict__ sUt, const bf16* __restrict__ sWt, const float* __restrict__ b2s,
    const void* __restrict__ empty_params, const void* __restrict__ empty_members,
    const void* __restrict__ tabR, int tabRf,
    const int* __restrict__ fpi, const int* __restrict__ fri,
    const int* __restrict__ ppi, const int* __restrict__ spi,
    void* __restrict__ out, long memfnEB, long tabEB,
    bf16* __restrict__ shadowW,
    const int* __restrict__ flagp, int mode)
{
  __shared__ __align__(16) bf16 hT[2][32][136];
  __shared__ __align__(16) bf16 xT[2][32][136];
  __shared__ __align__(16) bf16 feT[4][32][136];

  const int isf32 = *flagp;
  const int rf = (tabRf < 0) ? isf32 : tabRf;
  const int tid = threadIdx.x;
  const int w = tid >> 6;
  const int l15 = tid & 15;
  const int quad = (tid & 63) >> 4;
  const int gc = w*16 + quad*4;
  const int prow = tid >> 4;          // 0..31
  const int pc8 = (tid & 15) * 8;
  const int c0 = blockIdx.x * 32;

  bf16x8 AU[3][4], AW[3][4];
  f32x4 zb, rb, nbx, nbh;
  auto loadWB = [&](const bf16* Ut, const bf16* Wt, const float* b2) {
#pragma unroll
    for (int tr = 0; tr < 3; tr++)
#pragma unroll
      for (int kt = 0; kt < 4; kt++) {
        size_t o = (size_t)(tr*128 + w*16 + l15)*128 + kt*32 + quad*8;
        AU[tr][kt] = *(const bf16x8*)&Ut[o];
        AW[tr][kt] = *(const bf16x8*)&Wt[o];
      }
    zb  = *(const f32x4*)&b2[0*128 + gc];
    rb  = *(const f32x4*)&b2[1*128 + gc];
    nbx = *(const f32x4*)&b2[2*128 + gc];
    nbh = *(const f32x4*)&b2[3*128 + gc];
  };

  f32x4 hm[2];   // member result, carried into super phase

  // ================= Phase A: fn GRU + fe (NT=2, 32 seqs/pass) ==============
  loadWB(pUt, pWt, b2p);
  bf16x8 eP = ldx8(empty_params, pc8, isf32);   // hoisted: same every pass

  auto fnpass = [&](long s, int4 piv, int riv, int p) {
    // issue long-cover gathers immediately: x for step 1, and the ret row
    bf16x8 pend0 = ldx8(tabR, (long)piv.x*128 + pc8, rf);
    bf16x8 retv  = ldx8(tabR, (long)riv*128 + pc8, rf);
    *(bf16x8*)&xT[0][prow][pc8] = eP;
    bar();

    f32x4 h[2];
#pragma unroll
    for (int nt = 0; nt < 2; nt++) { h[nt][0]=0.f; h[nt][1]=0.f; h[nt][2]=0.f; h[nt][3]=0.f; }
    bf16x8 pend1;
    int buf = 0;
#pragma unroll
    for (int t = 0; t < 5; t++) {
      if (t < 3) {   // issue x for step t+2
        int rn = (t==0) ? piv.y : (t==1) ? piv.z : piv.w;
        pend1 = ldx8(tabR, (long)rn*128 + pc8, rf);
      }
      if (t == 0)
        gru_step<2,true >(AU, AW, zb, rb, nbx, nbh,
                          (const bf16(*)[136])hT[buf], (const bf16(*)[136])xT[0],
                          l15, quad, gc, h, hT[1-buf]);
      else
        gru_step<2,false>(AU, AW, zb, rb, nbx, nbh,
                          (const bf16(*)[136])hT[buf], (const bf16(*)[136])xT[t&1],
                          l15, quad, gc, h, hT[1-buf]);
      if (t < 4) { *(bf16x8*)&xT[(t+1)&1][prow][pc8] = pend0; pend0 = pend1; }
      bar();
      buf ^= 1;
    }
    // stage ret row (prefetched at pass start) into xT[0]
    *(bf16x8*)&xT[0][prow][pc8] = retv;
    bar();

    // fe GEMM: out = [h | ret] @ W_fn  (K=256); final hT is in hT[buf]
    f32x4 acc[2];
#pragma unroll
    for (int nt = 0; nt < 2; nt++) { acc[nt][0]=0.f; acc[nt][1]=0.f; acc[nt][2]=0.f; acc[nt][3]=0.f; }
#pragma unroll
    for (int kt = 0; kt < 8; kt++) {
      bf16x8 A = *(const bf16x8*)&wtT[(size_t)(w*16 + l15)*256 + kt*32 + quad*8];
#pragma unroll
      for (int nt = 0; nt < 2; nt++) {
        bf16x8 B = (kt < 4) ? *(const bf16x8*)&hT[buf][nt*16 + l15][kt*32 + quad*8]
                            : *(const bf16x8*)&xT[0][nt*16 + l15][(kt-4)*32 + quad*8];
        acc[nt] = mfma16(A, B, acc[nt]);
      }
    }
#pragma unroll
    for (int nt = 0; nt < 2; nt++) {
      long so = mode ? ((long)blockIdx.x*32 + nt*16 + l15)
                     : ((long)(c0 + nt*16 + l15)*4 + p);
      st4(out, memfnEB + so*128 + gc, isf32, acc[nt]);
      if (!mode) *(bf16x4*)&feT[p][nt*16 + l15][gc] = b4(acc[nt]);
    }
    bar();   // protect xT/hT/feT before next pass / phase B
  };

  if (mode) {
    long s = (long)blockIdx.x*32 + prow;
    int4 p0 = *(const int4*)&fpi[s*4];
    int r0 = fri[s];
    fnpass(s, p0, r0, 0);
    return;
  }
  {
    long sB = (long)(c0 + prow)*4;
    int4 p0 = *(const int4*)&fpi[(sB+0)*4];
    int4 p1 = *(const int4*)&fpi[(sB+1)*4];
    int4 p2 = *(const int4*)&fpi[(sB+2)*4];
    int4 p3 = *(const int4*)&fpi[(sB+3)*4];
    int4 rr = *(const int4*)&fri[sB];
    fnpass(sB+0, p0, rr.x, 0);
    fnpass(sB+1, p1, rr.y, 1);
    fnpass(sB+2, p2, rr.z, 2);
    fnpass(sB+3, p3, rr.w, 3);
  }

  // ================= Phase B: member GRU (T=13) =============================
  loadWB(mUt, mWt, b2m);
  int4 ma  = *(const int4*)&ppi[(size_t)(c0 + prow)*8];
  int4 mb2 = *(const int4*)&ppi[(size_t)(c0 + prow)*8 + 4];
  bf16x8 pendB0 = ldx8(tabR, (long)ma.x*128 + pc8, rf);   // x for step 1
  bf16x8 eM = ldx8(empty_members, pc8, isf32);
  *(bf16x8*)&xT[0][prow][pc8] = eM;
  bar();

#pragma unroll
  for (int nt = 0; nt < 2; nt++) { hm[nt][0]=0.f; hm[nt][1]=0.f; hm[nt][2]=0.f; hm[nt][3]=0.f; }
  {
    bf16x8 pendB1;
    int buf = 0;
#pragma unroll
    for (int t = 0; t < 13; t++) {
      if (t < 7) {   // issue x for step t+2 (prop rows rM[t+1])
        int rn = (t==0)?ma.y:(t==1)?ma.z:(t==2)?ma.w:(t==3)?mb2.x:(t==4)?mb2.y:(t==5)?mb2.z:mb2.w;
        pendB1 = ldx8(tabR, (long)rn*128 + pc8, rf);
      }
      const bf16 (*xb)[136] = (t < 9) ? (const bf16(*)[136])xT[t&1]
                                      : (const bf16(*)[136])feT[t-9];
      if (t == 0)
        gru_step<2,true >(AU, AW, zb, rb, nbx, nbh,
                          (const bf16(*)[136])hT[buf], xb, l15, quad, gc, hm, hT[1-buf]);
      else
        gru_step<2,false>(AU, AW, zb, rb, nbx, nbh,
                          (const bf16(*)[136])hT[buf], xb, l15, quad, gc, hm, hT[1-buf]);
      if (t < 8) { *(bf16x8*)&xT[(t+1)&1][prow][pc8] = pendB0; pendB0 = pendB1; }
      bar();
      buf ^= 1;
    }
  }

  // ================= Phase C: super GRU (T=5) ===============================
  loadWB(sUt, sWt, b2s);
  int4 sa = *(const int4*)&spi[(size_t)(c0 + prow)*4];
  bf16x8 x0v    = ldx8(tabR, (long)sa.x*128 + pc8, rf);
  bf16x8 pendC0 = ldx8(tabR, (long)sa.y*128 + pc8, rf);   // x for step 1
  *(bf16x8*)&xT[0][prow][pc8] = x0v;
  bar();

  f32x4 hs[2];
#pragma unroll
  for (int nt = 0; nt < 2; nt++) { hs[nt][0]=0.f; hs[nt][1]=0.f; hs[nt][2]=0.f; hs[nt][3]=0.f; }
  {
    bf16x8 pendC1;
    int buf = 0;
#pragma unroll
    for (int t = 0; t < 5; t++) {
      if (t < 2) {   // issue x for step t+2 (rows rS[t+2])
        int rn = (t==0) ? sa.z : sa.w;
        pendC1 = ldx8(tabR, (long)rn*128 + pc8, rf);
      }
      if (t == 0)
        gru_step<2,true >(AU, AW, zb, rb, nbx, nbh,
                          (const bf16(*)[136])hT[buf], (const bf16(*)[136])xT[0],
                          l15, quad, gc, hs, hT[1-buf]);
      else
        gru_step<2,false>(AU, AW, zb, rb, nbx, nbh,
                          (const bf16(*)[136])hT[buf], (const bf16(*)[136])xT[t&1],
                          l15, quad, gc, hs, hT[1-buf]);
      if (t < 3) { *(bf16x8*)&xT[(t+1)&1][prow][pc8] = pendC0; pendC0 = pendC1; }
      else if (t == 3) {   // stage m (registers) as x for step 4
#pragma unroll
        for (int nt = 0; nt < 2; nt++) *(bf16x4*)&xT[0][nt*16 + l15][gc] = b4(hm[nt]);
      }
      bar();
      buf ^= 1;
    }
  }
#pragma unroll
  for (int nt = 0; nt < 2; nt++) {
    long row = (long)(c0 + nt*16 + l15);
    st4(out, tabEB + row*128 + gc, isf32, hs[nt]);
    if (shadowW) *(bf16x4*)&shadowW[row*128 + gc] = b4(hs[nt]);
  }
}

// ---------------------------------------------------------------------------
// dtype detect: bf16-interpret first 128 u16 of basic_emb; any exponent>=128
// (|v|>=2) is impossible for genuine bf16 data here -> storage is float32.
// ---------------------------------------------------------------------------
__global__ void detect_kernel(const void* be, int* flag) {
  if (threadIdx.x == 0 && blockIdx.x == 0) {
    const unsigned short* u = (const unsigned short*)be;
    int f = 0;
    for (int i = 0; i < 128; i++) {
      unsigned e = (u[i] >> 7) & 0xFF;
      if (e >= 128) f = 1;
    }
    *flag = f;
  }
}

__global__ void convert_kernel(const void* pW, const void* pU, const void* mW, const void* mU,
                               const void* sW, const void* sU, const void* W_fn,
                               const void* pb, const void* mb, const void* sb,
                               bf16* pWt, bf16* pUt, bf16* mWt, bf16* mUt,
                               bf16* sWt, bf16* sUt, bf16* wtT,
                               float* b2p, float* b2m, float* b2s,
                               const int* flagp) {
  const int f = *flagp;
  int i = blockIdx.x*256 + threadIdx.x;
  const int TT = 384*128;
  if (i < 6*TT) {
    int which = i / TT, j = i - which*TT;
    int c = j >> 7, k = j & 127;
    const void* src = (which==0)?pW:(which==1)?pU:(which==2)?mW:(which==3)?mU:(which==4)?sW:sU;
    bf16* dst = (which==0)?pWt:(which==1)?pUt:(which==2)?mWt:(which==3)?mUt:(which==4)?sWt:sUt;
    dst[c*128 + k] = (bf16)ldf(src, (long)k*384 + c, f);
    return;
  }
  i -= 6*TT;
  if (i < 128*256) { int c = i >> 8, k = i & 255; wtT[c*256 + k] = (bf16)ldf(W_fn, (long)k*128 + c, f); return; }
  i -= 128*256;
  if (i < 3*512) {
    int which = i >> 9, j = i & 511;
    const void* b = (which==0)?pb:(which==1)?mb:sb;
    float* dst = (which==0)?b2p:(which==1)?b2m:b2s;
    int g = j >> 7, cc = j & 127;
    float v;
    if (g == 0)      v = ldf(b, cc, f)       + ldf(b, 384 + cc, f);
    else if (g == 1) v = ldf(b, 128 + cc, f) + ldf(b, 512 + cc, f);
    else if (g == 2) v = ldf(b, 256 + cc, f);
    else             v = ldf(b, 640 + cc, f);
    dst[j] = v;
  }
}

__global__ void level0_kernel(const int* __restrict__ basic_ids, const void* basic_emb,
                              void* out, bf16* __restrict__ shadow,
                              const int* __restrict__ flagp) {
  const int f = *flagp;
  int i = blockIdx.x*256 + threadIdx.x;   // < C*32
  int row = i >> 5, c4 = (i & 31) * 4;
  f32x4 v = ld4f(basic_emb, (long)basic_ids[row]*128 + c4, f);
  st4(out, (long)row*128 + c4, f, v);
  if (shadow) *(bf16x4*)&shadow[(long)row*128 + c4] = b4(v);
}

// ---------------------------------------------------------------------------
extern "C" void kernel_launch(void* const* d_in, const int* in_sizes, int n_in,
                              void* d_out, int out_size, void* d_ws, size_t ws_size,
                              hipStream_t stream) {
  const int* basic_ids      = (const int*)d_in[0];
  const int* prop_idx       = (const int*)d_in[1];
  const int* func_param_idx = (const int*)d_in[2];
  const int* func_ret_idx   = (const int*)d_in[3];
  const int* super_idx      = (const int*)d_in[4];
  const int* glob_param_idx = (const int*)d_in[5];
  const int* glob_ret_idx   = (const int*)d_in[6];
  const void* basic_emb     = d_in[7];
  const void* empty_params  = d_in[8];
  const void* empty_members = d_in[9];
  const void* W_fn = d_in[10];
  const void* pW = d_in[11]; const void* pU = d_in[12]; const void* pb = d_in[13];
  const void* mW = d_in[14]; const void* mU = d_in[15]; const void* mb = d_in[16];
  const void* sW = d_in[17]; const void* sU = d_in[18]; const void* sb = d_in[19];

  // d_out element layout: table [NTOT*128] | glob [NF*128] | memfn [7*C*F*128]
  const long GB = (long)NTOT*128;
  const long MB0 = GB + (long)NF*128;
  auto FEB = [&](int l) { return MB0 + (long)(l-1)*C*F*128; };

  char* wp = (char*)d_ws;
  auto carve = [&](size_t bytes) { char* p = wp; wp += (bytes + 255) & ~(size_t)255; return p; };
  int*  flag = (int*)carve(256);
  bf16* pWt = (bf16*)carve(384*128*2);
  bf16* pUt = (bf16*)carve(384*128*2);
  bf16* mWt = (bf16*)carve(384*128*2);
  bf16* mUt = (bf16*)carve(384*128*2);
  bf16* sWt = (bf16*)carve(384*128*2);
  bf16* sUt = (bf16*)carve(384*128*2);
  bf16* wtT = (bf16*)carve(128*256*2);
  float* b2p = (float*)carve(512*4);
  float* b2m = (float*)carve(512*4);
  float* b2s = (float*)carve(512*4);
  bf16* shadow = (bf16*)carve((size_t)NTOT*128*2);   // bf16 mirror of table, ~16.8 MB

  const bool useShadow = ((size_t)(wp - (char*)d_ws) <= ws_size);
  const void* tabR = useShadow ? (const void*)shadow : (const void*)d_out;
  const int tabRf  = useShadow ? 0 : -1;             // -1: use detected dtype flag
  bf16* shadowL0   = useShadow ? shadow : (bf16*)nullptr;

  detect_kernel<<<1, 64, 0, stream>>>(basic_emb, flag);
  {
    int total = 6*384*128 + 128*256 + 3*512;
    convert_kernel<<<(total + 255)/256, 256, 0, stream>>>(pW, pU, mW, mU, sW, sU, W_fn,
                                                          pb, mb, sb,
                                                          pWt, pUt, mWt, mUt, sWt, sUt, wtT,
                                                          b2p, b2m, b2s, flag);
  }
  level0_kernel<<<(C*32)/256, 256, 0, stream>>>(basic_ids, basic_emb, d_out, shadowL0, flag);

  for (int l = 1; l < LVL; l++) {
    level_kernel<<<C/32, 512, 0, stream>>>(
        pUt, pWt, b2p, wtT, mUt, mWt, b2m, sUt, sWt, b2s,
        empty_params, empty_members,
        tabR, tabRf,
        func_param_idx + (size_t)(l-1)*C*F*K,
        func_ret_idx   + (size_t)(l-1)*C*F,
        prop_idx       + (size_t)(l-1)*C*P,
        super_idx      + (size_t)(l-1)*C*S,
        d_out, FEB(l), (long)l*C*128,
        useShadow ? shadow + (size_t)l*C*128 : (bf16*)nullptr,
        flag, 0);
  }

  // global functions (NF seqs, T=5, 32 seqs/block) -> glob
  level_kernel<<<NF/32, 512, 0, stream>>>(
      pUt, pWt, b2p, wtT, mUt, mWt, b2m, sUt, sWt, b2s,
      empty_params, empty_members,
      tabR, tabRf,
      glob_param_idx, glob_ret_idx, nullptr, nullptr,
      d_out, GB, 0, (bf16*)nullptr,
      flag, 1);
}